// Round 15
// baseline (29.452 us; speedup 1.0000x reference)
//
#include <hip/hip_runtime.h>
#include <stdint.h>

// Problem constants
constexpr int T = 2048;
constexpr int B = 8;
constexpr int C = 1024;
constexpr int H = 16;
constexpr int K = 31;
constexpr int BC = B * C;            // 8192 (b,c) columns; stride along T
constexpr int HALO = K - 1;          // 30

// Block = 64 channels x 128 time steps; 4 waves, wave w owns 32 times.
// Waves 1..3 receive their 30-halo from wave w-1 via a small LDS relay
// (register handoff, NOT tile staging); only wave 0 loads halo from global.
// Read amp: (128+30)/128 = 1.23x  (R11/R14 were 1.94x and fabric-bound).
constexpr int CPW = 64;              // channels per block (= per wave)
constexpr int TW = 32;               // times per wave
constexpr int WAVES = 4;
constexpr int TBLK = TW * WAVES;     // 128 times per block
constexpr int BLOCK = CPW * WAVES;   // 256 threads
constexpr int NCOL = BC / CPW;       // 128 column slices
constexpr int NTCH = T / TBLK;       // 16 time chunks
constexpr int NBLK = NCOL * NTCH;    // 2048 blocks -> 8192 waves (as R11)

// ---------------------------------------------------------------------------
// out[t,bc] = sum_{d=0..30} wr[d] * x[t-d, bc] + bias[c]
// wr[d] = softmax(w[h])[K-1-d]; wave spans one head -> SGPRs.
// ---------------------------------------------------------------------------
__global__ __launch_bounds__(BLOCK) void lconv_tbc_kernel(
        const float* __restrict__ x,
        const float* __restrict__ w,
        const float* __restrict__ bias,
        float* __restrict__ out) {
    __shared__ float hbuf[WAVES - 1][HALO][CPW];   // 23 KiB relay

    const int tid = threadIdx.x;
    const int wid = tid >> 6;
    const int lane = tid & 63;
    const int colslice = blockIdx.x & (NCOL - 1);  // fastest: column slice
    const int tch = blockIdx.x >> 7;               // log2(NCOL) = 7
    const int bc = colslice * CPW + lane;
    const int c = bc & (C - 1);
    const int h = __builtin_amdgcn_readfirstlane(c >> 6);  // wave-uniform
    const int t0b = tch * TBLK;                    // block's first output time
    const int tw = t0b + wid * TW;                 // wave's first output time
    const float* col = x + bc;

    const float bi = bias[c];

    // ---- Issue own loads (asm-pinned order): own[j] = x[tw + j] ----
    float own[TW];
    #pragma unroll
    for (int j = 0; j < TW; ++j) {
        const float* a = col + (tw + j) * BC;
        asm volatile("global_load_dword %0, %1, off" : "=v"(own[j]) : "v"(a));
    }
    // ---- Wave 0's halo from global: hal[j] = x[t0b - 30 + j] ----
    float hal[HALO];
    if (wid == 0) {
        if (tch == 0) {
            #pragma unroll
            for (int j = 0; j < HALO; ++j) hal[j] = 0.0f;
        } else {
            #pragma unroll
            for (int j = 0; j < HALO; ++j) {
                const float* a = col + (t0b - HALO + j) * BC;
                asm volatile("global_load_dword %0, %1, off"
                             : "=v"(hal[j]) : "v"(a));
            }
        }
    }

    // ---- Softmax in the load shadow (taps wave-uniform -> SGPRs) ----
    float tap[K];
    #pragma unroll
    for (int k = 0; k < K; ++k)
        tap[k] = __uint_as_float(__builtin_amdgcn_readfirstlane(
            __float_as_uint(w[h * K + k])));
    float m = tap[0];
    #pragma unroll
    for (int k = 1; k < K; ++k) m = fmaxf(m, tap[k]);
    float s = 0.0f;
    #pragma unroll
    for (int k = 0; k < K; ++k) s += __expf(tap[k] - m);
    const float inv = 1.0f / s;
    float wr[K];   // reversed taps, wave-uniform -> SGPRs
    #pragma unroll
    for (int d = 0; d < K; ++d)
        wr[d] = __uint_as_float(__builtin_amdgcn_readfirstlane(
            __float_as_uint(__expf(tap[K - 1 - d] - m) * inv)));

    // ---- Drain loads, then relay: wave w (w<3) publishes own[2..31]
    // (= x[tw+2 .. tw+31] = next wave's halo x[tw+32-30 .. tw+32-1]). ----
    asm volatile("s_waitcnt vmcnt(0)" ::: "memory");
    __builtin_amdgcn_sched_barrier(0);
    if (wid < WAVES - 1) {
        #pragma unroll
        for (int j = 0; j < HALO; ++j)
            hbuf[wid][j][lane] = own[j + 2];
    }
    __syncthreads();
    if (wid > 0) {
        #pragma unroll
        for (int j = 0; j < HALO; ++j)
            hal[j] = hbuf[wid - 1][j][lane];
    }

    // ---- 32 outputs x 31 FMAs; win[0..29]=hal, win[30+j]=own[j] ----
    const int base = tw * BC + bc;
    #pragma unroll
    for (int u = 0; u < TW; ++u) {
        float acc = bi;
        #pragma unroll
        for (int d = 0; d < K; ++d) {
            const int i = u - d;                 // win index 30+i
            const float v = (i >= 0) ? own[i] : hal[HALO + i];
            acc = fmaf(wr[d], v, acc);
        }
        __builtin_nontemporal_store(acc, &out[base + u * BC]);
    }
}

extern "C" void kernel_launch(void* const* d_in, const int* in_sizes, int n_in,
                              void* d_out, int out_size, void* d_ws, size_t ws_size,
                              hipStream_t stream) {
    const float* x = (const float*)d_in[0];      // [T, B, C]
    const float* w = (const float*)d_in[1];      // [H, 1, K]
    const float* bias = (const float*)d_in[2];   // [C]
    float* out = (float*)d_out;                  // [T, B, C]

    lconv_tbc_kernel<<<dim3(NBLK), dim3(BLOCK), 0, stream>>>(x, w, bias, out);
}

// Round 16
// 28.033 us; speedup vs baseline: 1.0506x; 1.0506x over previous
//
#include <hip/hip_runtime.h>
#include <stdint.h>

// Problem constants
constexpr int T = 2048;
constexpr int B = 8;
constexpr int C = 1024;
constexpr int H = 16;
constexpr int K = 31;
constexpr int BC = B * C;            // 8192, stride between time steps

// Tiling (R11 = best known, 28.0 us)
constexpr int TT = 32;               // outputs per thread
constexpr int NB = K - 1 + TT;       // 61 window slots
constexpr int BLOCK = 256;
constexpr int BLK_PER_CHUNK = BC / BLOCK;    // 32
constexpr int NCHUNK = T / TT;               // 64
constexpr int NBLK = BLK_PER_CHUNK * NCHUNK; // 2048

// ---------------------------------------------------------------------------
// out[t,b,c] = sum_{d=0..K-1} wr[d] * x[t-d, b, c] + bias[c]
// wr[d] = softmax(w[h])[K-1-d]  (head h is wave-uniform).
//
// EXACT R11 structure (28.0 us) with ONE change: output stores carry the
// full cache-bypass policy "sc0 sc1 nt" (system scope + non-temporal).
// Rationale: steady-state FETCH is 33 MB in every register-kernel round
// (R11/R13/R14/R15) even though x (64 MB) fits the 256 MB L3 — the 64 MB
// write stream allocating in L3 evicts ~half of x per pass. The plain nt
// bit (R11's __builtin_nontemporal_store) did not prevent this. If sc0 sc1
// streams writes past the MALL, x stays resident: FETCH -> ~0 and the HBM
// stream becomes write-dominated (~64 MB @ ~6 TB/s).
// ---------------------------------------------------------------------------
__global__ __launch_bounds__(BLOCK) void lconv_tbc_kernel(
        const float* __restrict__ x,
        const float* __restrict__ w,
        const float* __restrict__ bias,
        float* __restrict__ out) {
    const int tid = threadIdx.x;
    const int cb = blockIdx.x & (BLK_PER_CHUNK - 1);   // bc slice (fastest)
    const int chunk = blockIdx.x / BLK_PER_CHUNK;      // time chunk
    const int bc = cb * BLOCK + tid;                   // [0, BC)
    const int c = bc & (C - 1);
    const int h = __builtin_amdgcn_readfirstlane(c >> 6);  // wave-uniform head

    const int t0 = chunk * TT;
    const float* col = x + bc;          // per-lane column base

    // bias load first (drains before/with the window).
    const float bi = bias[c];

    // ---- Issue the window as pinned-order asm loads: buf[j] = x[t0-30+j] ----
    float buf[NB];
    if (chunk == 0) {
        #pragma unroll
        for (int j = 0; j < K - 1; ++j) buf[j] = 0.0f;
        #pragma unroll
        for (int j = K - 1; j < NB; ++j) {
            const float* a = col + (t0 + (j - (K - 1))) * BC;
            asm volatile("global_load_dword %0, %1, off"
                         : "=v"(buf[j]) : "v"(a));
        }
    } else {
        #pragma unroll
        for (int j = 0; j < NB; ++j) {
            const float* a = col + (t0 - (K - 1) + j) * BC;
            asm volatile("global_load_dword %0, %1, off"
                         : "=v"(buf[j]) : "v"(a));
        }
    }

    // ---- Register-lean softmax in the load shadow (taps -> SGPRs) ----
    float tap[K];
    #pragma unroll
    for (int k = 0; k < K; ++k)
        tap[k] = __uint_as_float(__builtin_amdgcn_readfirstlane(
            __float_as_uint(w[h * K + k])));
    float m = tap[0];
    #pragma unroll
    for (int k = 1; k < K; ++k) m = fmaxf(m, tap[k]);
    float s = 0.0f;
    #pragma unroll
    for (int k = 0; k < K; ++k) s += __expf(tap[k] - m);
    const float inv = 1.0f / s;
    float wr[K];   // reversed, wave-uniform -> SGPRs
    #pragma unroll
    for (int d = 0; d < K; ++d)
        wr[d] = __uint_as_float(__builtin_amdgcn_readfirstlane(
            __float_as_uint(__expf(tap[K - 1 - d] - m) * inv)));

    // ---- 32 outputs x 31 FMAs; buf consumed oldest-first (compiler's
    // exact per-register vmcnt tracking drains the queue incrementally).
    // Stores: system-scope non-temporal (sc0 sc1 nt) = stream past caches.
    const int base = t0 * BC + bc;      // element index fits int (max 16.8M)
    #pragma unroll
    for (int u = 0; u < TT; ++u) {
        float acc = bi;
        #pragma unroll
        for (int d = 0; d < K; ++d)
            acc = fmaf(wr[d], buf[K - 1 + u - d], acc);
        const float* a = out + base + u * BC;
        asm volatile("global_store_dword %0, %1, off sc0 sc1 nt"
                     :: "v"(a), "v"(acc) : "memory");
    }
}

extern "C" void kernel_launch(void* const* d_in, const int* in_sizes, int n_in,
                              void* d_out, int out_size, void* d_ws, size_t ws_size,
                              hipStream_t stream) {
    const float* x = (const float*)d_in[0];      // [T, B, C]
    const float* w = (const float*)d_in[1];      // [H, 1, K]
    const float* bias = (const float*)d_in[2];   // [C]
    float* out = (float*)d_out;                  // [T, B, C]

    lconv_tbc_kernel<<<dim3(NBLK), dim3(BLOCK), 0, stream>>>(x, w, bias, out);
}